// Round 1
// baseline (465.045 us; speedup 1.0000x reference)
//
#include <hip/hip_runtime.h>
#include <stdint.h>

#define NN 50000
#define EE 800000
#define DD 128
#define GG 16
#define CC 10

typedef unsigned short u16;
typedef __bf16 bf16x8 __attribute__((ext_vector_type(8)));
typedef float f32x4 __attribute__((ext_vector_type(4)));

__device__ inline u16 f2bf(float f) {
    unsigned u = __float_as_uint(f);
    u = u + 0x7fffu + ((u >> 16) & 1u);   // RNE
    return (u16)(u >> 16);
}
__device__ inline float bf2f(unsigned bits16) { return __uint_as_float(bits16 << 16); }

// ---------- utility kernels ----------
__global__ void zero_kernel(int* __restrict__ p, int n) {
    int i = blockIdx.x * 256 + threadIdx.x;
    if (i < n) p[i] = 0;
}

__global__ void cvt_kernel(const float* __restrict__ x, u16* __restrict__ y) {
    int i = (blockIdx.x * 256 + threadIdx.x) * 4;
    if (i >= NN * DD) return;
    float4 v = *(const float4*)(x + i);
    ushort4 o;
    o.x = f2bf(v.x); o.y = f2bf(v.y); o.z = f2bf(v.z); o.w = f2bf(v.w);
    *(ushort4*)(y + i) = o;
}

// transpose + bf16-cast the four 128x128 MLP weight matrices: Wt[m][j][k] = bf16(W[k][j])
__global__ void prepw_kernel(const float* __restrict__ a, const float* __restrict__ b,
                             const float* __restrict__ c, const float* __restrict__ d,
                             u16* __restrict__ wt) {
    int i = blockIdx.x * 256 + threadIdx.x;
    if (i >= 4 * DD * DD) return;
    int m = i >> 14, r = i & 16383, k = r >> 7, j = r & 127;
    const float* W = (m == 0) ? a : (m == 1) ? b : (m == 2) ? c : d;
    wt[(m << 14) + (j << 7) + k] = f2bf(W[(k << 7) + j]);
}

// ---------- CSR build (sort edges by dst) ----------
__global__ void hist_kernel(const int* __restrict__ dst, int* __restrict__ deg) {
    int e = blockIdx.x * 256 + threadIdx.x;
    if (e < EE) atomicAdd(&deg[dst[e]], 1);
}

__global__ __launch_bounds__(1024) void scan_kernel(const int* __restrict__ deg, int* __restrict__ offs) {
    __shared__ int tot[1024];
    const int CH = 49;                       // 1024*49 = 50176 >= NN
    int t = threadIdx.x;
    int base = t * CH;
    int loc[CH];
    int s = 0;
#pragma unroll
    for (int i = 0; i < CH; i++) {
        int idx = base + i;
        int v = (idx < NN) ? deg[idx] : 0;
        loc[i] = s; s += v;
    }
    tot[t] = s;
    __syncthreads();
    for (int off = 1; off < 1024; off <<= 1) {
        int x = (t >= off) ? tot[t - off] : 0;
        __syncthreads();
        tot[t] += x;
        __syncthreads();
    }
    int prefix = (t == 0) ? 0 : tot[t - 1];
#pragma unroll
    for (int i = 0; i < CH; i++) {
        int idx = base + i;
        if (idx < NN) offs[idx] = prefix + loc[i];
    }
    if (t == 1023) offs[NN] = tot[1023];
}

__global__ void scatter_kernel(const int* __restrict__ src, const int* __restrict__ dst,
                               const int* __restrict__ offs, int* __restrict__ cur,
                               int* __restrict__ ssrc) {
    int e = blockIdx.x * 256 + threadIdx.x;
    if (e >= EE) return;
    int d = dst[e];
    int pos = offs[d] + atomicAdd(&cur[d], 1);
    ssrc[pos] = src[e];
}

// graph boundaries via binary search on sorted graph_ids
__global__ void bounds_kernel(const int* __restrict__ gids, int* __restrict__ gstart) {
    int g = threadIdx.x;
    if (g > GG) return;
    int lo = 0, hi = NN;
    while (lo < hi) { int mid = (lo + hi) >> 1; if (gids[mid] < g) lo = mid + 1; else hi = mid; }
    gstart[g] = lo;
}

// ---------- fused GIN layer: gather + MLP(2 matmuls, relu) ----------
// block = 256 threads = 4 waves; wave owns 16 node rows; entirely wave-private (no barriers).
__global__ __launch_bounds__(256) void gin_kernel(
    const u16* __restrict__ Hin, const u16* __restrict__ Wt1, const float* __restrict__ b1,
    const u16* __restrict__ Wt2, const float* __restrict__ b2,
    const int* __restrict__ offs, const int* __restrict__ ssrc,
    u16* __restrict__ Hout) {
    __shared__ u16 zb[64][136];   // +8 pad: row stride 272B -> 4-bank shift/row, 2-way max (free)
    __shared__ u16 yb[64][136];
    const int wave = threadIdx.x >> 6;
    const int lane = threadIdx.x & 63;
    const int m16 = lane & 15;
    const int quad = lane >> 4;
    const int row0 = blockIdx.x * 64 + wave * 16;

    // ---- gather: z = h_self + sum_{incoming edges} h_src (fp32 accum, bf16 in/out)
    for (int i = 0; i < 16; i++) {
        int node = row0 + i;
        float ax = 0.f, ay = 0.f;
        if (node < NN) {
            unsigned v = *(const unsigned*)(Hin + (size_t)node * DD + lane * 2);
            ax = bf2f(v & 0xffffu) ; ay = __uint_as_float(v & 0xffff0000u);
            ax = __uint_as_float(v << 16);
            int e0 = offs[node], e1 = offs[node + 1];
            int e = e0;
            for (; e + 4 <= e1; e += 4) {
                int s0 = ssrc[e], s1 = ssrc[e + 1], s2 = ssrc[e + 2], s3 = ssrc[e + 3];
                unsigned v0 = *(const unsigned*)(Hin + (size_t)s0 * DD + lane * 2);
                unsigned v1 = *(const unsigned*)(Hin + (size_t)s1 * DD + lane * 2);
                unsigned v2 = *(const unsigned*)(Hin + (size_t)s2 * DD + lane * 2);
                unsigned v3 = *(const unsigned*)(Hin + (size_t)s3 * DD + lane * 2);
                ax += __uint_as_float(v0 << 16) + __uint_as_float(v1 << 16)
                    + __uint_as_float(v2 << 16) + __uint_as_float(v3 << 16);
                ay += __uint_as_float(v0 & 0xffff0000u) + __uint_as_float(v1 & 0xffff0000u)
                    + __uint_as_float(v2 & 0xffff0000u) + __uint_as_float(v3 & 0xffff0000u);
            }
            for (; e < e1; e++) {
                int s = ssrc[e];
                unsigned v4 = *(const unsigned*)(Hin + (size_t)s * DD + lane * 2);
                ax += __uint_as_float(v4 << 16);
                ay += __uint_as_float(v4 & 0xffff0000u);
            }
        }
        unsigned packed = (unsigned)f2bf(ax) | ((unsigned)f2bf(ay) << 16);
        *(unsigned*)&zb[wave * 16 + i][lane * 2] = packed;
    }

    // ---- GEMM1: y = relu(z @ W1 + b1)  (A from LDS, B=Wt1 from global/L1)
    bf16x8 afr[4];
#pragma unroll
    for (int kk = 0; kk < 4; kk++)
        afr[kk] = *(const bf16x8*)&zb[wave * 16 + m16][kk * 32 + quad * 8];
    f32x4 acc[8];
#pragma unroll
    for (int nt = 0; nt < 8; nt++) acc[nt] = (f32x4){0.f, 0.f, 0.f, 0.f};
#pragma unroll
    for (int kk = 0; kk < 4; kk++) {
#pragma unroll
        for (int nt = 0; nt < 8; nt++) {
            bf16x8 bfr = *(const bf16x8*)(Wt1 + ((nt * 16 + m16) << 7) + kk * 32 + quad * 8);
            acc[nt] = __builtin_amdgcn_mfma_f32_16x16x32_bf16(afr[kk], bfr, acc[nt], 0, 0, 0);
        }
    }
#pragma unroll
    for (int nt = 0; nt < 8; nt++) {
        int col = nt * 16 + m16;
        float bias = b1[col];
#pragma unroll
        for (int r = 0; r < 4; r++) {
            float yv = acc[nt][r] + bias;
            yv = yv > 0.f ? yv : 0.f;
            yb[wave * 16 + quad * 4 + r][col] = f2bf(yv);
        }
    }

    // ---- GEMM2: out = relu(y @ W2 + b2)  (wave-private yb, no barrier needed)
#pragma unroll
    for (int kk = 0; kk < 4; kk++)
        afr[kk] = *(const bf16x8*)&yb[wave * 16 + m16][kk * 32 + quad * 8];
#pragma unroll
    for (int nt = 0; nt < 8; nt++) acc[nt] = (f32x4){0.f, 0.f, 0.f, 0.f};
#pragma unroll
    for (int kk = 0; kk < 4; kk++) {
#pragma unroll
        for (int nt = 0; nt < 8; nt++) {
            bf16x8 bfr = *(const bf16x8*)(Wt2 + ((nt * 16 + m16) << 7) + kk * 32 + quad * 8);
            acc[nt] = __builtin_amdgcn_mfma_f32_16x16x32_bf16(afr[kk], bfr, acc[nt], 0, 0, 0);
        }
    }
#pragma unroll
    for (int nt = 0; nt < 8; nt++) {
        int col = nt * 16 + m16;
        float bias = b2[col];
#pragma unroll
        for (int r = 0; r < 4; r++) {
            float ov = acc[nt][r] + bias;
            ov = ov > 0.f ? ov : 0.f;
            int node = row0 + quad * 4 + r;
            if (node < NN) Hout[(size_t)node * DD + col] = f2bf(ov);
        }
    }
}

// ---------- mean-pool partial sums ----------
__global__ void pool_kernel(const u16* __restrict__ H2, const int* __restrict__ gstart,
                            float* __restrict__ pool) {
    int g = blockIdx.x >> 5, q = blockIdx.x & 31;
    int f = threadIdx.x;   // 0..127
    int s = gstart[g], e = gstart[g + 1];
    float sum = 0.f;
    for (int n = s + q; n < e; n += 32) sum += bf2f(H2[(size_t)n * DD + f]);
    atomicAdd(&pool[g * DD + f], sum);
}

// ---------- classifier (fp32) ----------
__global__ void cls_kernel(const float* __restrict__ pool, const int* __restrict__ gstart,
                           const float* __restrict__ Wc1, const float* __restrict__ bc1,
                           const float* __restrict__ Wc2, const float* __restrict__ bc2,
                           float* __restrict__ out) {
    __shared__ float hg[128];
    __shared__ float y1[128];
    int g = blockIdx.x;
    int t = threadIdx.x;   // 128 threads
    int cnt = gstart[g + 1] - gstart[g];
    float inv = 1.f / (float)(cnt > 1 ? cnt : 1);
    hg[t] = pool[g * DD + t] * inv;
    __syncthreads();
    float a = bc1[t];
    for (int k = 0; k < DD; k++) a += hg[k] * Wc1[k * DD + t];
    y1[t] = a > 0.f ? a : 0.f;
    __syncthreads();
    if (t < CC) {
        float o = bc2[t];
        for (int k = 0; k < DD; k++) o += y1[k] * Wc2[k * CC + t];
        out[g * CC + t] = o;
    }
}

extern "C" void kernel_launch(void* const* d_in, const int* in_sizes, int n_in,
                              void* d_out, int out_size, void* d_ws, size_t ws_size,
                              hipStream_t stream) {
    const float* h    = (const float*)d_in[0];
    const int*   src  = (const int*)d_in[1];
    const int*   dst  = (const int*)d_in[2];
    const int*   gids = (const int*)d_in[3];
    const float* W1a  = (const float*)d_in[4];
    const float* b1a  = (const float*)d_in[5];
    const float* W2a  = (const float*)d_in[6];
    const float* b2a  = (const float*)d_in[7];
    const float* W1b  = (const float*)d_in[8];
    const float* b1b  = (const float*)d_in[9];
    const float* W2b  = (const float*)d_in[10];
    const float* b2b  = (const float*)d_in[11];
    const float* Wc1  = (const float*)d_in[12];
    const float* bc1  = (const float*)d_in[13];
    const float* Wc2  = (const float*)d_in[14];
    const float* bc2  = (const float*)d_in[15];
    float* out = (float*)d_out;

    char* ws = (char*)d_ws;
    u16*   H0     = (u16*)(ws);                    // 12,800,000 B
    u16*   H1     = (u16*)(ws + 12800000);         // 12,800,000 B
    u16*   H2     = (u16*)(ws + 25600000);         // 12,800,000 B
    u16*   Wt     = (u16*)(ws + 38400000);         //    131,072 B (4 transposed bf16 mats)
    int*   deg    = (int*)(ws + 38531072);         //    200,000 B
    int*   cur    = (int*)(ws + 38731072);         //    200,000 B  (contiguous w/ deg)
    float* pool   = (float*)(ws + 38931072);       //      8,192 B  (contiguous w/ cur)
    int*   offs   = (int*)(ws + 38939264);         //    200,004 B
    int*   ssrc   = (int*)(ws + 39139268);         //  3,200,000 B
    int*   gstart = (int*)(ws + 42339268);         //         68 B   total ~42.3 MB

    // zero deg + cur + pool in one pass (they are laid out contiguously)
    zero_kernel<<<dim3((2 * NN + GG * DD + 255) / 256), dim3(256), 0, stream>>>(deg, 2 * NN + GG * DD);
    cvt_kernel<<<dim3((NN * DD / 4 + 255) / 256), dim3(256), 0, stream>>>(h, H0);
    prepw_kernel<<<dim3((4 * DD * DD + 255) / 256), dim3(256), 0, stream>>>(W1a, W2a, W1b, W2b, Wt);
    hist_kernel<<<dim3((EE + 255) / 256), dim3(256), 0, stream>>>(dst, deg);
    scan_kernel<<<dim3(1), dim3(1024), 0, stream>>>(deg, offs);
    scatter_kernel<<<dim3((EE + 255) / 256), dim3(256), 0, stream>>>(src, dst, offs, cur, ssrc);
    bounds_kernel<<<dim3(1), dim3(32), 0, stream>>>(gids, gstart);
    gin_kernel<<<dim3((NN + 63) / 64), dim3(256), 0, stream>>>(H0, Wt, b1a, Wt + 16384, b2a, offs, ssrc, H1);
    gin_kernel<<<dim3((NN + 63) / 64), dim3(256), 0, stream>>>(H1, Wt + 32768, b1b, Wt + 49152, b2b, offs, ssrc, H2);
    pool_kernel<<<dim3(GG * 32), dim3(128), 0, stream>>>(H2, gstart, pool);
    cls_kernel<<<dim3(GG), dim3(128), 0, stream>>>(pool, gstart, Wc1, bc1, Wc2, bc2, out);
}

// Round 3
// 340.668 us; speedup vs baseline: 1.3651x; 1.3651x over previous
//
#include <hip/hip_runtime.h>
#include <stdint.h>

#define NN 50000
#define EE 800000
#define DD 128
#define GG 16
#define CC 10
#define NB 196                    // scan blocks: 196*256 = 50176 >= NN

typedef unsigned short u16;
typedef __bf16 bf16x8 __attribute__((ext_vector_type(8)));
typedef float f32x4 __attribute__((ext_vector_type(4)));

__device__ inline u16 f2bf(float f) {
    unsigned u = __float_as_uint(f);
    u = u + 0x7fffu + ((u >> 16) & 1u);   // RNE
    return (u16)(u >> 16);
}
__device__ inline unsigned pack2(float a, float b) {
    return (unsigned)f2bf(a) | ((unsigned)f2bf(b) << 16);
}
__device__ inline float bf2f(unsigned bits16) { return __uint_as_float(bits16 << 16); }
__device__ inline void acc8(float* a, uint4 v) {
    a[0] += __uint_as_float(v.x << 16); a[1] += __uint_as_float(v.x & 0xffff0000u);
    a[2] += __uint_as_float(v.y << 16); a[3] += __uint_as_float(v.y & 0xffff0000u);
    a[4] += __uint_as_float(v.z << 16); a[5] += __uint_as_float(v.z & 0xffff0000u);
    a[6] += __uint_as_float(v.w << 16); a[7] += __uint_as_float(v.w & 0xffff0000u);
}

// ---------- fused prep: zero (deg|cur|pool), cvt h->bf16, transpose+cast weights ----------
#define PZ (2 * NN + GG * DD)          // 102048 ints to zero
#define PC (NN * DD / 4)               // 1600000 float4 groups
#define PW (4 * DD * DD)               // 65536 weight elements
#define PTOT (PZ + PC + PW)

__global__ void prep_kernel(const float* __restrict__ h,
                            const float* __restrict__ a, const float* __restrict__ b,
                            const float* __restrict__ c, const float* __restrict__ d,
                            int* __restrict__ zbase, u16* __restrict__ H0,
                            u16* __restrict__ wt) {
    int i = blockIdx.x * 256 + threadIdx.x;
    if (i < PZ) { zbase[i] = 0; return; }
    i -= PZ;
    if (i < PC) {
        int j = i * 4;
        float4 v = *(const float4*)(h + j);
        ushort4 o;
        o.x = f2bf(v.x); o.y = f2bf(v.y); o.z = f2bf(v.z); o.w = f2bf(v.w);
        *(ushort4*)(H0 + j) = o;
        return;
    }
    i -= PC;
    if (i < PW) {
        int m = i >> 14, r = i & 16383, k = r >> 7, j = r & 127;
        const float* W = (m == 0) ? a : (m == 1) ? b : (m == 2) ? c : d;
        wt[(m << 14) + (j << 7) + k] = f2bf(W[(k << 7) + j]);
    }
}

// ---------- CSR build ----------
__global__ void hist_kernel(const int* __restrict__ dst, int* __restrict__ deg) {
    int e = blockIdx.x * 256 + threadIdx.x;
    if (e < EE) atomicAdd(&deg[dst[e]], 1);
}

__global__ void scanA_kernel(const int* __restrict__ deg, int* __restrict__ offs,
                             int* __restrict__ bsum) {
    __shared__ int tmp[256];
    int t = threadIdx.x, idx = blockIdx.x * 256 + t;
    int v = (idx < NN) ? deg[idx] : 0;
    tmp[t] = v; __syncthreads();
    for (int off = 1; off < 256; off <<= 1) {
        int x = (t >= off) ? tmp[t - off] : 0;
        __syncthreads();
        tmp[t] += x;
        __syncthreads();
    }
    if (idx < NN) offs[idx] = tmp[t] - v;          // exclusive within block
    if (t == 255) bsum[blockIdx.x] = tmp[255];
}

// scans the NB block sums; also computes graph boundaries (fused)
__global__ void scanB_kernel(int* __restrict__ bsum, int* __restrict__ offs,
                             const int* __restrict__ gids, int* __restrict__ gstart) {
    __shared__ int tmp[256];
    int t = threadIdx.x;
    if (t <= GG) {                                  // graph boundary binary search
        int lo = 0, hi = NN;
        while (lo < hi) { int mid = (lo + hi) >> 1; if (gids[mid] < t) lo = mid + 1; else hi = mid; }
        gstart[t] = lo;
    }
    int v = (t < NB) ? bsum[t] : 0;
    tmp[t] = v; __syncthreads();
    for (int off = 1; off < 256; off <<= 1) {
        int x = (t >= off) ? tmp[t - off] : 0;
        __syncthreads();
        tmp[t] += x;
        __syncthreads();
    }
    if (t < NB) bsum[t] = tmp[t] - v;               // exclusive block offsets
    if (t == NB - 1) offs[NN] = tmp[t];             // grand total (= EE)
}

__global__ void scanC_kernel(int* __restrict__ offs, const int* __restrict__ bsum) {
    int idx = blockIdx.x * 256 + threadIdx.x;
    if (idx < NN) offs[idx] += bsum[blockIdx.x];
}

__global__ void scatter_kernel(const int* __restrict__ src, const int* __restrict__ dst,
                               const int* __restrict__ offs, int* __restrict__ cur,
                               int* __restrict__ ssrc) {
    int e = blockIdx.x * 256 + threadIdx.x;
    if (e >= EE) return;
    int d = dst[e];
    int pos = offs[d] + atomicAdd(&cur[d], 1);
    ssrc[pos] = src[e];
}

// ---------- fused GIN layer ----------
// block = 256 = 4 waves; wave owns 16 rows; fully wave-private (no __syncthreads).
// Gather: 8 groups of 8 lanes; group pair (2r,2r+1) covers one row's two 128B halves;
// each group walks its row's edge list with unroll-4 -> up to 32 outstanding loads/wave.
__global__ __launch_bounds__(256) void gin_kernel(
    const u16* __restrict__ Hin, const u16* __restrict__ Wt1, const float* __restrict__ b1,
    const u16* __restrict__ Wt2, const float* __restrict__ b2,
    const int* __restrict__ offs, const int* __restrict__ ssrc,
    u16* __restrict__ Hout) {
    __shared__ u16 zb[64][136];   // row stride 272B = 17*16 -> 16B-aligned vec access, 4-bank rotation
    __shared__ u16 yb[64][136];
    const int wave = threadIdx.x >> 6;
    const int lane = threadIdx.x & 63;
    const int m16 = lane & 15;
    const int quad = lane >> 4;
    const int row0 = blockIdx.x * 64 + wave * 16;

    const int g8 = lane >> 3;          // 0..7
    const int lid8 = lane & 7;         // 0..7
    const int rsel = g8 >> 1;          // row-within-4
    const int foff = (g8 & 1) * 64 + lid8 * 8;   // feature offset (8 bf16 = 16B)

    for (int i = 0; i < 4; i++) {
        const int tr = i * 4 + rsel;   // tile row 0..15
        const int node = row0 + tr;
        float acc[8] = {0.f, 0.f, 0.f, 0.f, 0.f, 0.f, 0.f, 0.f};
        int e = 0, e1 = 0;
        if (node < NN) {
            uint4 v = *(const uint4*)(Hin + (size_t)node * DD + foff);
            acc8(acc, v);              // self term (eps=0)
            e = offs[node]; e1 = offs[node + 1];
        }
        for (; e + 4 <= e1; e += 4) {
            int s0 = ssrc[e], s1 = ssrc[e + 1], s2 = ssrc[e + 2], s3 = ssrc[e + 3];
            uint4 v0 = *(const uint4*)(Hin + (size_t)s0 * DD + foff);
            uint4 v1 = *(const uint4*)(Hin + (size_t)s1 * DD + foff);
            uint4 v2 = *(const uint4*)(Hin + (size_t)s2 * DD + foff);
            uint4 v3 = *(const uint4*)(Hin + (size_t)s3 * DD + foff);
            acc8(acc, v0); acc8(acc, v1); acc8(acc, v2); acc8(acc, v3);
        }
        for (; e < e1; e++) {
            int s = ssrc[e];
            uint4 v = *(const uint4*)(Hin + (size_t)s * DD + foff);
            acc8(acc, v);
        }
        uint4 o;
        o.x = pack2(acc[0], acc[1]); o.y = pack2(acc[2], acc[3]);
        o.z = pack2(acc[4], acc[5]); o.w = pack2(acc[6], acc[7]);
        *(uint4*)&zb[wave * 16 + tr][foff] = o;
    }

    // ---- GEMM1: y = relu(z @ W1 + b1)
    bf16x8 afr[4];
#pragma unroll
    for (int kk = 0; kk < 4; kk++)
        afr[kk] = *(const bf16x8*)&zb[wave * 16 + m16][kk * 32 + quad * 8];
    f32x4 acc[8];
#pragma unroll
    for (int nt = 0; nt < 8; nt++) acc[nt] = (f32x4){0.f, 0.f, 0.f, 0.f};
#pragma unroll
    for (int kk = 0; kk < 4; kk++) {
#pragma unroll
        for (int nt = 0; nt < 8; nt++) {
            bf16x8 bfr = *(const bf16x8*)(Wt1 + ((nt * 16 + m16) << 7) + kk * 32 + quad * 8);
            acc[nt] = __builtin_amdgcn_mfma_f32_16x16x32_bf16(afr[kk], bfr, acc[nt], 0, 0, 0);
        }
    }
#pragma unroll
    for (int nt = 0; nt < 8; nt++) {
        int col = nt * 16 + m16;
        float bias = b1[col];
#pragma unroll
        for (int r = 0; r < 4; r++) {
            float yv = acc[nt][r] + bias;
            yv = yv > 0.f ? yv : 0.f;
            yb[wave * 16 + quad * 4 + r][col] = f2bf(yv);
        }
    }

    // ---- GEMM2: out = relu(y @ W2 + b2)
#pragma unroll
    for (int kk = 0; kk < 4; kk++)
        afr[kk] = *(const bf16x8*)&yb[wave * 16 + m16][kk * 32 + quad * 8];
#pragma unroll
    for (int nt = 0; nt < 8; nt++) acc[nt] = (f32x4){0.f, 0.f, 0.f, 0.f};
#pragma unroll
    for (int kk = 0; kk < 4; kk++) {
#pragma unroll
        for (int nt = 0; nt < 8; nt++) {
            bf16x8 bfr = *(const bf16x8*)(Wt2 + ((nt * 16 + m16) << 7) + kk * 32 + quad * 8);
            acc[nt] = __builtin_amdgcn_mfma_f32_16x16x32_bf16(afr[kk], bfr, acc[nt], 0, 0, 0);
        }
    }
    // stage in LDS (reuse zb), then dwordx4 coalesced stores
#pragma unroll
    for (int nt = 0; nt < 8; nt++) {
        int col = nt * 16 + m16;
        float bias = b2[col];
#pragma unroll
        for (int r = 0; r < 4; r++) {
            float ov = acc[nt][r] + bias;
            ov = ov > 0.f ? ov : 0.f;
            zb[wave * 16 + quad * 4 + r][col] = f2bf(ov);
        }
    }
#pragma unroll
    for (int p = 0; p < 4; p++) {
        int tr = p * 4 + quad;
        int node = row0 + tr;
        int c = m16 * 8;
        if (node < NN)
            *(uint4*)(Hout + (size_t)node * DD + c) = *(const uint4*)&zb[wave * 16 + tr][c];
    }
}

// ---------- mean-pool partial sums ----------
__global__ void pool_kernel(const u16* __restrict__ H2, const int* __restrict__ gstart,
                            float* __restrict__ pool) {
    int g = blockIdx.x >> 5, q = blockIdx.x & 31;
    int f = threadIdx.x;   // 0..127
    int s = gstart[g], e = gstart[g + 1];
    float sum = 0.f;
    for (int n = s + q; n < e; n += 32) sum += bf2f(H2[(size_t)n * DD + f]);
    atomicAdd(&pool[g * DD + f], sum);
}

// ---------- classifier (fp32) ----------
__global__ void cls_kernel(const float* __restrict__ pool, const int* __restrict__ gstart,
                           const float* __restrict__ Wc1, const float* __restrict__ bc1,
                           const float* __restrict__ Wc2, const float* __restrict__ bc2,
                           float* __restrict__ out) {
    __shared__ float hg[128];
    __shared__ float y1[128];
    int g = blockIdx.x;
    int t = threadIdx.x;   // 128 threads
    int cnt = gstart[g + 1] - gstart[g];
    float inv = 1.f / (float)(cnt > 1 ? cnt : 1);
    hg[t] = pool[g * DD + t] * inv;
    __syncthreads();
    float a = bc1[t];
    for (int k = 0; k < DD; k++) a += hg[k] * Wc1[k * DD + t];
    y1[t] = a > 0.f ? a : 0.f;
    __syncthreads();
    if (t < CC) {
        float o = bc2[t];
        for (int k = 0; k < DD; k++) o += y1[k] * Wc2[k * CC + t];
        out[g * CC + t] = o;
    }
}

extern "C" void kernel_launch(void* const* d_in, const int* in_sizes, int n_in,
                              void* d_out, int out_size, void* d_ws, size_t ws_size,
                              hipStream_t stream) {
    const float* h    = (const float*)d_in[0];
    const int*   src  = (const int*)d_in[1];
    const int*   dst  = (const int*)d_in[2];
    const int*   gids = (const int*)d_in[3];
    const float* W1a  = (const float*)d_in[4];
    const float* b1a  = (const float*)d_in[5];
    const float* W2a  = (const float*)d_in[6];
    const float* b2a  = (const float*)d_in[7];
    const float* W1b  = (const float*)d_in[8];
    const float* b1b  = (const float*)d_in[9];
    const float* W2b  = (const float*)d_in[10];
    const float* b2b  = (const float*)d_in[11];
    const float* Wc1  = (const float*)d_in[12];
    const float* bc1  = (const float*)d_in[13];
    const float* Wc2  = (const float*)d_in[14];
    const float* bc2  = (const float*)d_in[15];
    float* out = (float*)d_out;

    char* ws = (char*)d_ws;
    u16*   H0     = (u16*)(ws);                    // 12,800,000 B
    u16*   H1     = (u16*)(ws + 12800000);         // 12,800,000 B
    u16*   H2     = (u16*)(ws + 25600000);         // 12,800,000 B
    u16*   Wt     = (u16*)(ws + 38400000);         // 131,072 B
    int*   deg    = (int*)(ws + 38531072);         // 200,000 B (zero range start)
    int*   cur    = (int*)(ws + 38731072);         // 200,000 B (contiguous with deg)
    float* pool   = (float*)(ws + 38931072);       // 8,192 B (contiguous with cur)
    int*   offs   = (int*)(ws + 38939264);         // 200,004 B
    int*   ssrc   = (int*)(ws + 39139268);         // 3,200,000 B
    int*   gstart = (int*)(ws + 42339268);         // 68 B
    int*   bsum   = (int*)(ws + 25600000);         // aliases H2 (dead until gin layer 2)

    prep_kernel<<<dim3((PTOT + 255) / 256), dim3(256), 0, stream>>>(h, W1a, W2a, W1b, W2b, deg, H0, Wt);
    hist_kernel<<<dim3((EE + 255) / 256), dim3(256), 0, stream>>>(dst, deg);
    scanA_kernel<<<dim3(NB), dim3(256), 0, stream>>>(deg, offs, bsum);
    scanB_kernel<<<dim3(1), dim3(256), 0, stream>>>(bsum, offs, gids, gstart);
    scanC_kernel<<<dim3(NB), dim3(256), 0, stream>>>(offs, bsum);
    scatter_kernel<<<dim3((EE + 255) / 256), dim3(256), 0, stream>>>(src, dst, offs, cur, ssrc);
    gin_kernel<<<dim3((NN + 63) / 64), dim3(256), 0, stream>>>(H0, Wt, b1a, Wt + 16384, b2a, offs, ssrc, H1);
    gin_kernel<<<dim3((NN + 63) / 64), dim3(256), 0, stream>>>(H1, Wt + 32768, b1b, Wt + 49152, b2b, offs, ssrc, H2);
    pool_kernel<<<dim3(GG * 32), dim3(128), 0, stream>>>(H2, gstart, pool);
    cls_kernel<<<dim3(GG), dim3(128), 0, stream>>>(pool, gstart, Wc1, bc1, Wc2, bc2, out);
}